// Round 8
// baseline (416.086 us; speedup 1.0000x reference)
//
#include <hip/hip_runtime.h>
#include <cstdint>
#include <cstddef>

#define H 128
#define PSTRIDE 512   // packed row, interleaved by feature-quad: q*16 + [ch4|cc4|uf4|ah4]

typedef __bf16 v8bf __attribute__((ext_vector_type(8)));
typedef __bf16 v4bf __attribute__((ext_vector_type(4)));
typedef float  v4f  __attribute__((ext_vector_type(4)));

__device__ __forceinline__ float ftanh(float x) {
    return 1.f - 2.f / (1.f + __expf(2.f * x));
}
__device__ __forceinline__ float fsigm(float x) {
    return 1.f / (1.f + __expf(-x));
}

// 32-lane sum reduce: 4 DPP adds (VALU pipe, cheap) + 1 ds_swizzle xor16.
__device__ __forceinline__ float red32(float s) {
    int x;
    x = __builtin_amdgcn_update_dpp(0, __float_as_int(s), 0xB1, 0xF, 0xF, true);  // quad_perm xor1
    s += __int_as_float(x);
    x = __builtin_amdgcn_update_dpp(0, __float_as_int(s), 0x4E, 0xF, 0xF, true);  // quad_perm xor2
    s += __int_as_float(x);
    x = __builtin_amdgcn_update_dpp(0, __float_as_int(s), 0x141, 0xF, 0xF, true); // row_half_mirror
    s += __int_as_float(x);
    x = __builtin_amdgcn_update_dpp(0, __float_as_int(s), 0x140, 0xF, 0xF, true); // row_mirror
    s += __int_as_float(x);
    x = __builtin_amdgcn_ds_swizzle(__float_as_int(s), 0x401F);                   // xor16
    return s + __int_as_float(x);
}

struct MatDesc {
    const __bf16* A;    // bf16 A, stride lda
    int           lda;
    const __bf16* Wb;   // [128,128] bf16 [n][k]
    const float*  bias; // [128] or nullptr
    __bf16*       C;    // contiguous bf16 out, stride ldc
    int           ldc;
};
struct MatBatch { MatDesc m[5]; };
struct WPtrs { const float* w[10]; };

// ---------------- prep: wconv (10 mats) + convert x + edge histogram ----------------
__global__ __launch_bounds__(256) void prep_k(WPtrs wp, __bf16* __restrict__ Wb,
                                              const float* __restrict__ x,
                                              __bf16* __restrict__ xe,
                                              const int* __restrict__ ci,
                                              int* __restrict__ counts,
                                              int MH4, int L) {
    int tid = blockIdx.x * 256 + threadIdx.x;
    if (tid < 40960) {  // 10 * 4096 v4-chunks of weights
        int mat = tid >> 12;
        int off = (tid & 4095) << 2;
        v4f a = *(const v4f*)(wp.w[mat] + off);
        v4bf b;
#pragma unroll
        for (int k = 0; k < 4; ++k) b[k] = (__bf16)a[k];
        *(v4bf*)(Wb + mat * 16384 + off) = b;
        return;
    }
    int i = tid - 40960;
    if (i < MH4) {
        v4f a = ((const v4f*)x)[i];
        v4bf ab;
#pragma unroll
        for (int k = 0; k < 4; ++k) ab[k] = (__bf16)a[k];
        ((v4bf*)xe)[i] = ab;
        return;
    }
    int l = i - MH4;
    if (l < L) atomicAdd(&counts[ci[l]], 1);
}

// ---------------- pair GEMM: Ah (child_h@Wa^T+b) and Ufh (child_h@Uf^T) together ----------------
// Writes COMPLETE interleaved P quads [ch4|cc4|uf4|ah4] (32B) -> full-line stores,
// no RMW amplification. n-split in half (nh) for occupancy; swizzle pairs the two
// halves of a tile on the same XCD so chh f32 reads are L2-shared.
__global__ __launch_bounds__(256) void pair_k(const float* __restrict__ chh,
                                              const float* __restrict__ chc,
                                              const __bf16* __restrict__ Wa,
                                              const __bf16* __restrict__ Uf,
                                              const float* __restrict__ bia,
                                              __bf16* __restrict__ P,
                                              int M, int ntile) {
    const int blk = blockIdx.x;
    const int w16 = blk % 16;
    const int t   = (blk / 16) * 8 + (w16 & 7);
    const int nh  = w16 >> 3;            // column half: n in [nh*64, nh*64+64)
    if (t >= ntile) return;

    __shared__ __bf16 lds[2][64][136];   // weights, then reused as output staging

    for (int tt = threadIdx.x; tt < 2048; tt += 256) {
        int ws = tt >> 10;
        int ln = (tt >> 4) & 63;
        int k  = (tt & 15) << 3;
        const __bf16* src = ws ? Uf : Wa;
        *(v8bf*)&lds[ws][ln][k] = *(const v8bf*)(src + (nh * 64 + ln) * H + k);
    }
    __syncthreads();

    const int wave = threadIdx.x >> 6;
    const int lane = threadIdx.x & 63;
    const int quad = lane >> 4;
    const int l16  = lane & 15;
    const int r0   = t * 128 + wave * 32;

    int ra = r0 + l16;      if (ra > M - 1) ra = M - 1;
    int rb = r0 + 16 + l16; if (rb > M - 1) rb = M - 1;

    const float* p0 = chh + (size_t)ra * H + quad * 8;
    const float* p1 = chh + (size_t)rb * H + quad * 8;
    v8bf a0[4], a1[4];
#pragma unroll
    for (int k0 = 0; k0 < 4; ++k0) {
        v4f x0a = *(const v4f*)(p0 + k0 * 32);
        v4f x0b = *(const v4f*)(p0 + k0 * 32 + 4);
        v4f x1a = *(const v4f*)(p1 + k0 * 32);
        v4f x1b = *(const v4f*)(p1 + k0 * 32 + 4);
        v8bf t0, t1;
#pragma unroll
        for (int k = 0; k < 4; ++k) {
            t0[k] = (__bf16)x0a[k]; t0[k + 4] = (__bf16)x0b[k];
            t1[k] = (__bf16)x1a[k]; t1[k + 4] = (__bf16)x1b[k];
        }
        a0[k0] = t0; a1[k0] = t1;
    }

    v4f acc[2][4][2];
#pragma unroll
    for (int ws = 0; ws < 2; ++ws)
#pragma unroll
        for (int ntl = 0; ntl < 4; ++ntl)
#pragma unroll
            for (int rg = 0; rg < 2; ++rg) acc[ws][ntl][rg] = (v4f){0.f, 0.f, 0.f, 0.f};

#pragma unroll
    for (int k0 = 0; k0 < 4; ++k0) {
#pragma unroll
        for (int ntl = 0; ntl < 4; ++ntl) {
            v8bf bwa = *(const v8bf*)(&lds[0][ntl * 16 + l16][k0 * 32 + quad * 8]);
            v8bf buf = *(const v8bf*)(&lds[1][ntl * 16 + l16][k0 * 32 + quad * 8]);
            acc[0][ntl][0] = __builtin_amdgcn_mfma_f32_16x16x32_bf16(a0[k0], bwa, acc[0][ntl][0], 0, 0, 0);
            acc[0][ntl][1] = __builtin_amdgcn_mfma_f32_16x16x32_bf16(a1[k0], bwa, acc[0][ntl][1], 0, 0, 0);
            acc[1][ntl][0] = __builtin_amdgcn_mfma_f32_16x16x32_bf16(a0[k0], buf, acc[1][ntl][0], 0, 0, 0);
            acc[1][ntl][1] = __builtin_amdgcn_mfma_f32_16x16x32_bf16(a1[k0], buf, acc[1][ntl][1], 0, 0, 0);
        }
    }
    __syncthreads();   // weights fully consumed; reuse LDS as staging

    __bf16 (*stg)[128][68] = reinterpret_cast<__bf16 (*)[128][68]>(&lds[0][0][0]);
#pragma unroll
    for (int ws = 0; ws < 2; ++ws)
#pragma unroll
        for (int ntl = 0; ntl < 4; ++ntl) {
            int lcol = ntl * 16 + l16;
            float bv = (ws == 0) ? bia[nh * 64 + lcol] : 0.f;
#pragma unroll
            for (int rg = 0; rg < 2; ++rg)
#pragma unroll
                for (int r = 0; r < 4; ++r) {
                    int lrow = wave * 32 + rg * 16 + quad * 4 + r;
                    stg[ws][lrow][lcol] = (__bf16)(acc[ws][ntl][rg][r] + bv);
                }
        }
    __syncthreads();

    // write P: 128 rows x 16 local quads, 32B each, full line coverage
    for (int id = threadIdx.x; id < 2048; id += 256) {
        int lrow = id >> 4;
        int lq   = id & 15;
        int m = t * 128 + lrow;
        if (m >= M) continue;
        int q = nh * 16 + lq;
        v4f hv = *(const v4f*)(chh + (size_t)m * H + q * 4);
        v4f cv = *(const v4f*)(chc + (size_t)m * H + q * 4);
        v8bf o0, o1;
#pragma unroll
        for (int kk = 0; kk < 4; ++kk) {
            o0[kk]     = (__bf16)hv[kk];            // ch
            o0[4 + kk] = (__bf16)cv[kk];            // cc
            o1[kk]     = stg[1][lrow][lq * 4 + kk]; // uf
            o1[4 + kk] = stg[0][lrow][lq * 4 + kk]; // ah
        }
        __bf16* dst = P + (size_t)m * PSTRIDE + ((size_t)q << 4);
        *(v8bf*)dst = o0;
        *(v8bf*)(dst + 8) = o1;
    }
}

// ---------------- batched GEMM (5 x-mats): 1-D grid, tile-grouped XCD swizzle ----------------
__global__ __launch_bounds__(256) void gemm_batch(MatBatch batch, int M, int ntile) {
    const int blk = blockIdx.x;
    const int g = blk / 40;
    const int w = blk % 40;
    const int j = w >> 3;             // mat 0..4
    const int t = (g << 3) | (w & 7); // tile
    if (t >= ntile) return;
    const MatDesc d = batch.m[j];
    __shared__ __bf16 wlds[H][H + 8];

    for (int tt = threadIdx.x; tt < 2048; tt += 256) {
        int n = tt >> 4;
        int k = (tt & 15) << 3;
        *(v8bf*)&wlds[n][k] = *(const v8bf*)(d.Wb + n * H + k);
    }
    __syncthreads();

    const int wave = threadIdx.x >> 6;
    const int lane = threadIdx.x & 63;
    const int quad = lane >> 4;
    const int l16  = lane & 15;
    const int r0   = t * 128 + wave * 32;

    int ra = r0 + l16;      if (ra > M - 1) ra = M - 1;
    int rb = r0 + 16 + l16; if (rb > M - 1) rb = M - 1;

    const __bf16* p0 = d.A + (size_t)ra * d.lda + quad * 8;
    const __bf16* p1 = d.A + (size_t)rb * d.lda + quad * 8;
    v8bf a0[4], a1[4];
#pragma unroll
    for (int k0 = 0; k0 < 4; ++k0) {
        a0[k0] = *(const v8bf*)(p0 + k0 * 32);
        a1[k0] = *(const v8bf*)(p1 + k0 * 32);
    }

    v4f acc0[8], acc1[8];
#pragma unroll
    for (int nt = 0; nt < 8; ++nt) {
        acc0[nt] = (v4f){0.f, 0.f, 0.f, 0.f};
        acc1[nt] = (v4f){0.f, 0.f, 0.f, 0.f};
    }

#pragma unroll
    for (int k0 = 0; k0 < 4; ++k0) {
#pragma unroll
        for (int nt = 0; nt < 8; ++nt) {
            v8bf b = *(const v8bf*)(&wlds[nt * 16 + l16][k0 * 32 + quad * 8]);
            acc0[nt] = __builtin_amdgcn_mfma_f32_16x16x32_bf16(a0[k0], b, acc0[nt], 0, 0, 0);
            acc1[nt] = __builtin_amdgcn_mfma_f32_16x16x32_bf16(a1[k0], b, acc1[nt], 0, 0, 0);
        }
    }

#pragma unroll
    for (int nt = 0; nt < 8; ++nt) {
        int n = nt * 16 + l16;
        float bia = d.bias ? d.bias[n] : 0.f;
#pragma unroll
        for (int r = 0; r < 4; ++r) {
            int m0 = r0 + quad * 4 + r;
            int m1 = m0 + 16;
            if (m0 < M) d.C[(size_t)m0 * d.ldc + n] = (__bf16)(acc0[nt][r] + bia);
            if (m1 < M) d.C[(size_t)m1 * d.ldc + n] = (__bf16)(acc1[nt][r] + bia);
        }
    }
}

// ---------------- scans ----------------
__global__ __launch_bounds__(1024) void scan_local(const int* __restrict__ counts,
                                                   int* __restrict__ excl,
                                                   int* __restrict__ bsums, int M) {
    __shared__ int s[1024];
    int tid = threadIdx.x;
    int idx = blockIdx.x * 1024 + tid;
    int v = (idx < M) ? counts[idx] : 0;
    s[tid] = v;
    __syncthreads();
    for (int off = 1; off < 1024; off <<= 1) {
        int t = (tid >= off) ? s[tid - off] : 0;
        __syncthreads();
        s[tid] += t;
        __syncthreads();
    }
    if (idx < M) excl[idx] = s[tid] - v;
    if (tid == 1023) bsums[blockIdx.x] = s[1023];
}

__global__ __launch_bounds__(1024) void scan_fused(int* __restrict__ rowptr,
                                                   int* __restrict__ cursor,
                                                   const int* __restrict__ bsums,
                                                   const int* __restrict__ counts,
                                                   int M, int nb) {
    __shared__ int s[1024];
    int t = threadIdx.x, b = blockIdx.x;
    int v = (t < nb) ? bsums[t] : 0;
    s[t] = v;
    __syncthreads();
    for (int off = 1; off < 1024; off <<= 1) {
        int tt = (t >= off) ? s[t - off] : 0;
        __syncthreads();
        s[t] += tt;
        __syncthreads();
    }
    int boff = (b == 0) ? 0 : s[b - 1];
    int idx = b * 1024 + t;
    if (idx < M) {
        int val = rowptr[idx] + boff;
        rowptr[idx] = val;
        cursor[idx] = val;
        if (idx == M - 1) rowptr[M] = val + counts[M - 1];
    }
}

// ---------------- scatter: CSR payload = child index ----------------
__global__ __launch_bounds__(256) void scatter_k(const int* __restrict__ ci,
                                                 const int* __restrict__ chi,
                                                 int* __restrict__ cursor,
                                                 int* __restrict__ payload, int L) {
    int l = blockIdx.x * 256 + threadIdx.x;
    if (l < L) {
        int pos = atomicAdd(&cursor[ci[l]], 1);
        payload[pos] = chi[l];
    }
}

// ---------------- fused attention + segment reduce, SINGLE PASS, load-prefetch pipeline ----------------
// 32 lanes/segment, 4 feats/lane. Per edge: 2 x b128 interleaved P read; next edge's
// loads are issued BEFORE the current edge's compute (load-only pipeline: +8 VGPR,
// no duplicated compute -> avoids the R4 occupancy regression).
__global__ __launch_bounds__(128) void segment_fused(const int* __restrict__ rowptr,
                                                     const int* __restrict__ payload,
                                                     const float* __restrict__ vw,
                                                     const __bf16* __restrict__ Bx,
                                                     const __bf16* __restrict__ Wfx,
                                                     const __bf16* __restrict__ P,
                                                     __bf16* __restrict__ hhat,
                                                     float* __restrict__ sumfc, int M) {
    const int wl   = threadIdx.x & 63;
    const int half = wl & 32;
    const int l32  = wl & 31;
    const int m = blockIdx.x * 4 + (threadIdx.x >> 5);
    if (m >= M) return;
    const int start = rowptr[m];
    const int deg   = rowptr[m + 1] - start;
    const int h   = l32 << 2;
    const int q16 = l32 << 4;

    v4bf bx4 = *(const v4bf*)(Bx + (m << 7) + h);
    v4bf wf4 = *(const v4bf*)(Wfx + (m << 7) + h);
    v4f  vv  = *(const v4f*)(vw + h);
    float bxf[4], wff[4];
#pragma unroll
    for (int k = 0; k < 4; ++k) { bxf[k] = (float)bx4[k]; wff[k] = (float)wf4[k]; }

    // batch payload loads (1 per lane per 32 edges)
    int pl0 = (l32 < deg) ? payload[start + l32] : 0;
    int pl1 = (32 + l32 < deg) ? payload[start + 32 + l32] : 0;

    float denom = 0.f;
    float acch[4] = {0.f, 0.f, 0.f, 0.f};
    float accf[4] = {0.f, 0.f, 0.f, 0.f};

    const int jcap = deg < 64 ? deg : 64;
    if (jcap > 0) {
        int cj0 = __shfl(pl0, half, 64);
        const __bf16* pb0 = P + ((size_t)cj0 << 9) + q16;
        v8bf x0 = *(const v8bf*)pb0;
        v8bf x1 = *(const v8bf*)(pb0 + 8);
        for (int j = 0; j < jcap; ++j) {
            v8bf y0 = x0, y1 = x1;
            int jn = j + 1;
            if (jn < jcap) {
                int cjn = __shfl((jn & 32) ? pl1 : pl0, half | (jn & 31), 64);
                const __bf16* pbn = P + ((size_t)cjn << 9) + q16;
                x0 = *(const v8bf*)pbn;
                x1 = *(const v8bf*)(pbn + 8);
            }
            float s = 0.f;
#pragma unroll
            for (int k = 0; k < 4; ++k) s += ftanh((float)y1[4 + k] + bxf[k]) * vv[k];
            s = red32(s);
            float ex = __expf(s);
            denom += ex;
#pragma unroll
            for (int k = 0; k < 4; ++k) {
                acch[k] = fmaf(ex, (float)y0[k], acch[k]);
                accf[k] += fsigm(wff[k] + (float)y1[k]) * (float)y0[4 + k];
            }
        }
    }
    // rare tail (deg > 64)
    for (int j = 64; j < deg; ++j) {
        int cj = payload[start + j];
        const __bf16* pb = P + ((size_t)cj << 9) + q16;
        v8bf x0 = *(const v8bf*)pb;
        v8bf x1 = *(const v8bf*)(pb + 8);
        float s = 0.f;
#pragma unroll
        for (int k = 0; k < 4; ++k) s += ftanh((float)x1[4 + k] + bxf[k]) * vv[k];
        s = red32(s);
        float ex = __expf(s);
        denom += ex;
#pragma unroll
        for (int k = 0; k < 4; ++k) {
            acch[k] = fmaf(ex, (float)x0[k], acch[k]);
            accf[k] += fsigm(wff[k] + (float)x1[k]) * (float)x0[4 + k];
        }
    }

    float inv = 1.f / (denom + 1e-9f);
    v4bf hb;
    v4f sf;
#pragma unroll
    for (int k = 0; k < 4; ++k) { hb[k] = (__bf16)(acch[k] * inv); sf[k] = accf[k]; }
    *(v4bf*)(hhat + (size_t)m * H + h) = hb;
    *(v4f*)(sumfc + (size_t)m * H + h) = sf;
}

// ---------------- fused gemm2 (hhat @ {Ui,Uc,Uo}) + LSTM epilogue, NO LDS, y-split ----------------
__global__ __launch_bounds__(256) void gemm_final(const __bf16* __restrict__ hhat,
                                                  const __bf16* __restrict__ Ui,
                                                  const __bf16* __restrict__ Uc,
                                                  const __bf16* __restrict__ Uo,
                                                  const __bf16* __restrict__ Xi,
                                                  const __bf16* __restrict__ Xc,
                                                  const __bf16* __restrict__ Xo,
                                                  const float* __restrict__ sumfc,
                                                  float* __restrict__ out, int M, int MH) {
    const int wave = threadIdx.x >> 6;
    const int lane = threadIdx.x & 63;
    const int quad = lane >> 4;
    const int l16  = lane & 15;
    const int r0   = blockIdx.x * 128 + wave * 32;
    const int nt0  = blockIdx.y * 2;

    const __bf16* p0 = hhat + (size_t)(r0 + l16) * H + quad * 8;
    const __bf16* p1 = hhat + (size_t)(r0 + 16 + l16) * H + quad * 8;
    v8bf a0[4], a1[4];
#pragma unroll
    for (int k0 = 0; k0 < 4; ++k0) {
        a0[k0] = *(const v8bf*)(p0 + k0 * 32);
        a1[k0] = *(const v8bf*)(p1 + k0 * 32);
    }

#pragma unroll
    for (int ntl = 0; ntl < 2; ++ntl) {
        const int nt = nt0 + ntl;
        const int boff = (nt * 16 + l16) * H + quad * 8;
        v4f ai0 = (v4f){0.f, 0.f, 0.f, 0.f}, ai1 = ai0;
        v4f ac0 = ai0, ac1 = ai0, ao0 = ai0, ao1 = ai0;
#pragma unroll
        for (int k0 = 0; k0 < 4; ++k0) {
            v8bf bi = *(const v8bf*)(Ui + boff + k0 * 32);
            v8bf bc = *(const v8bf*)(Uc + boff + k0 * 32);
            v8bf bo = *(const v8bf*)(Uo + boff + k0 * 32);
            ai0 = __builtin_amdgcn_mfma_f32_16x16x32_bf16(a0[k0], bi, ai0, 0, 0, 0);
            ai1 = __builtin_amdgcn_mfma_f32_16x16x32_bf16(a1[k0], bi, ai1, 0, 0, 0);
            ac0 = __builtin_amdgcn_mfma_f32_16x16x32_bf16(a0[k0], bc, ac0, 0, 0, 0);
            ac1 = __builtin_amdgcn_mfma_f32_16x16x32_bf16(a1[k0], bc, ac1, 0, 0, 0);
            ao0 = __builtin_amdgcn_mfma_f32_16x16x32_bf16(a0[k0], bo, ao0, 0, 0, 0);
            ao1 = __builtin_amdgcn_mfma_f32_16x16x32_bf16(a1[k0], bo, ao1, 0, 0, 0);
        }
        int n = nt * 16 + l16;
#pragma unroll
        for (int r = 0; r < 4; ++r) {
            int m0 = r0 + quad * 4 + r;
            if (m0 < M) {
                size_t idx = (size_t)m0 * H + n;
                float ig = fsigm((float)Xi[idx] + ai0[r]);
                float ct = ftanh((float)Xc[idx] + ac0[r]);
                float og = fsigm((float)Xo[idx] + ao0[r]);
                float c = ig * ct + sumfc[idx];
                out[idx] = og * ftanh(c);
                out[MH + idx] = c;
            }
            int m1 = m0 + 16;
            if (m1 < M) {
                size_t idx = (size_t)m1 * H + n;
                float ig = fsigm((float)Xi[idx] + ai1[r]);
                float ct = ftanh((float)Xc[idx] + ac1[r]);
                float og = fsigm((float)Xo[idx] + ao1[r]);
                float c = ig * ct + sumfc[idx];
                out[idx] = og * ftanh(c);
                out[MH + idx] = c;
            }
        }
    }
}

extern "C" void kernel_launch(void* const* d_in, const int* in_sizes, int n_in,
                              void* d_out, int out_size, void* d_ws, size_t ws_size,
                              hipStream_t stream) {
    const float* x_emb   = (const float*)d_in[0];
    const float* child_h = (const float*)d_in[1];
    const float* child_c = (const float*)d_in[2];
    const int*   ci      = (const int*)d_in[3];
    const int*   chi     = (const int*)d_in[4];
    const float* Wi_b = (const float*)d_in[15];
    const float* Wf_b = (const float*)d_in[16];
    const float* Wo_b = (const float*)d_in[17];
    const float* Wc_b = (const float*)d_in[18];
    const float* Wa_b = (const float*)d_in[19];
    const float* vw   = (const float*)d_in[20];

    const int M    = in_sizes[0] / H;
    const int L    = in_sizes[3];
    const int Mpad = (M + 127) & ~127;
    const int MH   = M * H;
    const int MH4  = MH / 4;

    char* p = (char*)d_ws;
    auto alloc = [&](size_t bytes) {
        char* r = p;
        p += (bytes + 255) & ~(size_t)255;
        return (void*)r;
    };
    size_t bfbytes = (size_t)Mpad * H * sizeof(__bf16);
    __bf16* xe16   = (__bf16*)alloc(bfbytes);
    __bf16* P      = (__bf16*)alloc((size_t)Mpad * PSTRIDE * sizeof(__bf16));
    __bf16* hhat16 = (__bf16*)alloc(bfbytes);
    __bf16* Bx16   = (__bf16*)alloc(bfbytes);
    __bf16* Wfx16  = (__bf16*)alloc(bfbytes);
    __bf16* Xi16   = (__bf16*)alloc(bfbytes);
    __bf16* Xc16   = (__bf16*)alloc(bfbytes);
    __bf16* Xo16   = (__bf16*)alloc(bfbytes);
    __bf16* Wb     = (__bf16*)alloc(10 * 16384 * sizeof(__bf16));
    float* sumfc   = (float*)alloc((size_t)MH * 4);
    int*   payload = (int*)alloc((size_t)L * 4);
    int*   counts  = (int*)alloc((size_t)M * 4);
    int*   rowptr  = (int*)alloc((size_t)(M + 1) * 4);
    int*   cursor  = (int*)alloc((size_t)M * 4);
    int*   bsums   = (int*)alloc(1024 * 4);

    hipMemsetAsync(counts, 0, (size_t)M * 4, stream);

    WPtrs wp;
    for (int k = 0; k < 10; ++k) wp.w[k] = (const float*)d_in[5 + k];
    int prep_items = 40960 + MH4 + L;
    prep_k<<<(prep_items + 255) / 256, 256, 0, stream>>>(wp, Wb, x_emb, xe16,
                                                         ci, counts, MH4, L);

    const __bf16* Wi = Wb + 0 * 16384;
    const __bf16* Ui = Wb + 1 * 16384;
    const __bf16* Wf = Wb + 2 * 16384;
    const __bf16* Uf = Wb + 3 * 16384;
    const __bf16* Wo = Wb + 4 * 16384;
    const __bf16* Uo = Wb + 5 * 16384;
    const __bf16* Wc = Wb + 6 * 16384;
    const __bf16* Uc = Wb + 7 * 16384;
    const __bf16* Wa = Wb + 8 * 16384;
    const __bf16* Ua = Wb + 9 * 16384;

    const int ntile = Mpad / 128;
    const int ntile8 = (ntile + 7) & ~7;

    pair_k<<<2 * ntile8, 256, 0, stream>>>(child_h, child_c, Wa, Uf, Wa_b, P, M, ntile);

    MatBatch ba{};
    ba.m[0] = MatDesc{xe16, H, Ua, nullptr, Bx16,  H};
    ba.m[1] = MatDesc{xe16, H, Wf, Wf_b,    Wfx16, H};
    ba.m[2] = MatDesc{xe16, H, Wi, Wi_b,    Xi16,  H};
    ba.m[3] = MatDesc{xe16, H, Wc, Wc_b,    Xc16,  H};
    ba.m[4] = MatDesc{xe16, H, Wo, Wo_b,    Xo16,  H};
    gemm_batch<<<5 * ntile8, 256, 0, stream>>>(ba, M, ntile);

    int nb = (M + 1023) / 1024;
    scan_local<<<nb, 1024, 0, stream>>>(counts, rowptr, bsums, M);
    scan_fused<<<nb, 1024, 0, stream>>>(rowptr, cursor, bsums, counts, M, nb);

    scatter_k<<<(L + 255) / 256, 256, 0, stream>>>(ci, chi, cursor, payload, L);

    segment_fused<<<(M + 3) / 4, 128, 0, stream>>>(rowptr, payload, vw, Bx16, Wfx16, P,
                                                   hhat16, sumfc, M);

    gemm_final<<<dim3(Mpad / 128, 4), 256, 0, stream>>>(hhat16, Ui, Uc, Uo, Xi16, Xc16, Xo16,
                                                        sumfc, (float*)d_out, M, MH);
}